// Round 2
// baseline (27775.861 us; speedup 1.0000x reference)
//
#include <hip/hip_runtime.h>
#include <stdint.h>
#include <stddef.h>

#define B_ 128
#define T_ 512
#define E_ 300
#define H_ 300
#define NG 1200   // 4H
#define KP 320    // padded K (300 -> 320)
#define M_ 65536  // B_*T_

typedef float f32x4 __attribute__((ext_vector_type(4)));
typedef short s16x8 __attribute__((ext_vector_type(8)));

static __device__ __forceinline__ unsigned short f2bf(float f){
  union { float f; unsigned u; } x; x.f = f;
  unsigned r = x.u + 0x7fffu + ((x.u >> 16) & 1u);  // RNE
  return (unsigned short)(r >> 16);
}
static __device__ __forceinline__ float bf2f(unsigned short u){
  union { unsigned u; float f; } x; x.u = ((unsigned)u) << 16;
  return x.f;
}
static __device__ __forceinline__ void gload_lds16(const void* g, void* l){
  __builtin_amdgcn_global_load_lds((const __attribute__((address_space(1))) unsigned int*)g,
                                   (__attribute__((address_space(3))) unsigned int*)l, 16, 0, 0);
}
static __device__ __forceinline__ float sigf(float x){ return 1.f/(1.f + __expf(-x)); }
static __device__ __forceinline__ float tanhfast(float x){ return 2.f/(1.f + __expf(-2.f*x)) - 1.f; }

// ---------------- lengths + proximity weights ----------------
__global__ void k_len_prox(const int* __restrict__ text, const int* __restrict__ aspect,
                           const int* __restrict__ left, int* __restrict__ lens,
                           float* __restrict__ wprox){
  int b = blockIdx.x; int lane = threadIdx.x;
  int c1=0,c2=0,c3=0;
  for(int t=lane;t<T_;t+=64){
    c1 += (text[b*T_+t]!=0); c2 += (aspect[b*T_+t]!=0); c3 += (left[b*T_+t]!=0);
  }
  #pragma unroll
  for(int o=32;o>0;o>>=1){ c1+=__shfl_down(c1,o); c2+=__shfl_down(c2,o); c3+=__shfl_down(c3,o); }
  __shared__ int sl[3];
  if(lane==0){ sl[0]=c1; sl[1]=c2; sl[2]=c3; lens[b]=c1; lens[128+b]=c2; lens[256+b]=c3; }
  __syncthreads();
  float tl=(float)sl[0]; float a0=(float)sl[2]; float a1=a0+(float)sl[1]-1.f; float ctx=tl-(float)sl[1];
  for(int t=lane;t<T_;t+=64){
    float j=(float)t, w;
    if(j<a0) w = 1.f-(a0-j)/ctx;
    else if(j<=a1) w = 0.f;
    else if(j<tl) w = 1.f-(j-a1)/ctx;
    else w = 0.f;
    wprox[b*T_+t]=w;
  }
}

// ---------------- embedding gather (fwd + length-reversed), bf16, K padded ----------------
__global__ void k_emb(const int* __restrict__ text, const float* __restrict__ emb,
                      const int* __restrict__ lens, unsigned short* __restrict__ embp){
  int m = blockIdx.x; int b = m>>9; int t = m&511; int lane=threadIdx.x;
  int idxf = text[m];
  int len = lens[b];
  int idxb = (t<len)? text[b*T_ + (len-1-t)] : -1;
  const float* rf = emb + (size_t)idxf*E_;
  const float* rb = emb + (size_t)(idxb<0?0:idxb)*E_;
  unsigned short* of = embp + (size_t)m*KP;
  unsigned short* ob = embp + ((size_t)M_ + m)*KP;
  for(int k=lane;k<KP;k+=64){
    of[k] = (k<E_)? f2bf(rf[k]) : (unsigned short)0;
    ob[k] = (k<E_ && idxb>=0)? f2bf(rb[k]) : (unsigned short)0;
  }
}

// ---------------- conv weight repack: cwp[kap][o][i] (o padded 640, i padded 608) ----------------
__global__ void k_cw(const float* __restrict__ cw, unsigned short* __restrict__ out){
  int rid = blockIdx.x; int kap = rid/640; int o = rid-kap*640; int lane=threadIdx.x;
  unsigned short* dst = out + ((size_t)kap*640 + o)*608;
  for(int i=lane;i<608;i+=64)
    dst[i] = (o<600 && i<600)? f2bf(cw[((size_t)o*600+i)*3 + kap]) : (unsigned short)0;
}

// ---------------- persistent bidirectional LSTM (fused input GEMM) ----------------
// COOPERATIVE launch, grid 256 = slice s(16) x [d(2)*group g(8)]; blockIdx = s*16 + (d*8+g).
// Each WG: 16 batch rows x 19 hidden dims; W_ih AND W_hh slices in registers (B-frags);
// h exchanged via global double-buffer + device-scope flag per 16-WG group.
__global__ __launch_bounds__(320) void k_lstm(const unsigned short* __restrict__ embp,
        const float* __restrict__ wihf, const float* __restrict__ whhf, const float* __restrict__ bf,
        const float* __restrict__ wihb, const float* __restrict__ whhb, const float* __restrict__ bb,
        const int* __restrict__ lens, const float* __restrict__ wprox,
        unsigned short* __restrict__ hexch, unsigned int* __restrict__ flags,
        unsigned short* __restrict__ hpad){
  int bid = blockIdx.x;
  int s = bid >> 4;
  int grp = bid & 15;
  int d = grp >> 3, g = grp & 7;
  int tid = threadIdx.x, lane = tid & 63, wid = tid >> 6;
  int kgrp = lane >> 4;
  int n = wid*16 + (lane & 15);           // local gate index 0..79 (76 used)
  int q = n/19, jj = n - q*19;
  bool vn = (n < 76) && (s*19 + jj < 300);
  int grow = q*300 + s*19 + jj;           // W_ih / W_hh row = gate index
  const float* Wih  = d ? wihb : wihf;
  const float* Whh  = d ? whhb : whhf;
  const float* bias = d ? bb : bf;
  s16x8 wifrag[10], whfrag[10];
  #pragma unroll
  for(int c=0;c<10;c++){
    s16x8 vi, vh;
    #pragma unroll
    for(int r=0;r<8;r++){
      int k = c*32 + kgrp*8 + r;
      float fi = (vn && k < E_) ? Wih[(size_t)grow*E_ + k] : 0.f;
      float fh = (vn && k < H_) ? Whh[(size_t)grow*H_ + k] : 0.f;
      vi[r] = (short)f2bf(fi);
      vh[r] = (short)f2bf(fh);
    }
    wifrag[c] = vi; whfrag[c] = vh;
  }
  float bias_v = vn ? bias[grow] : 0.f;
  // epilogue thread mapping: 16 rows x 19 dims
  int erow = tid/19, ej = tid - erow*19;
  bool act = (tid < 304) && (s*19 + ej < 300);
  int eb = g*16 + (erow & 15);
  int edim = s*19 + ej;
  int elen = act ? lens[eb] : 1;
  float c_reg = 0.f;
  // staging map: 640 16B-segments = 16 rows x 40 segs; 2 per thread
  int sid0 = tid*2, sid1 = tid*2+1;
  int srow0 = sid0/40, scol0 = (sid0 - srow0*40)*8;
  int srow1 = sid1/40, scol1 = (sid1 - srow1*40)*8;
  __shared__ __align__(16) unsigned short h_lds[16][328];  // +8 pad: spreads row->bank
  __shared__ __align__(16) unsigned short e_lds[16][328];
  __shared__ float gates_lds[80][16];
  unsigned short* hx = hexch + (size_t)grp*(2*16*KP);
  unsigned int* flag = flags + grp;
  const unsigned short* ebase = embp + (size_t)d*M_*KP;
  size_t eg0 = ((size_t)(g*16 + srow0)*T_)*KP + scol0;
  size_t eg1 = ((size_t)(g*16 + srow1)*T_)*KP + scol1;
  size_t hpf = ((size_t)eb*528 + 8)*608 + edim;
  for(int t=0;t<T_;t++){
    // issue e-tile loads early (independent of peers) — hide under the spin
    int4 ev0 = *(const int4*)&ebase[eg0 + (size_t)t*KP];
    int4 ev1 = *(const int4*)&ebase[eg1 + (size_t)t*KP];
    if(t>0){
      if(tid==0){
        unsigned tgt = 16u*(unsigned)t;
        while(__hip_atomic_load(flag, __ATOMIC_ACQUIRE, __HIP_MEMORY_SCOPE_AGENT) < tgt)
          __builtin_amdgcn_s_sleep(1);
      }
      __syncthreads();
      __threadfence();   // acquire side: make peers' h stores visible to all lanes
    }
    const unsigned short* src = hx + (size_t)(t&1)*16*KP;
    *(int4*)&h_lds[srow0][scol0] = *(const int4*)&src[srow0*KP + scol0];
    *(int4*)&h_lds[srow1][scol1] = *(const int4*)&src[srow1*KP + scol1];
    *(int4*)&e_lds[srow0][scol0] = ev0;
    *(int4*)&e_lds[srow1][scol1] = ev1;
    __syncthreads();
    f32x4 acc_e = {bias_v,bias_v,bias_v,bias_v};
    f32x4 acc_h = {0.f,0.f,0.f,0.f};
    #pragma unroll
    for(int c=0;c<10;c++){
      s16x8 ae = *(const s16x8*)&e_lds[lane&15][c*32 + kgrp*8];
      s16x8 ah = *(const s16x8*)&h_lds[lane&15][c*32 + kgrp*8];
      acc_e = __builtin_amdgcn_mfma_f32_16x16x32_bf16(ae, wifrag[c], acc_e, 0,0,0);
      acc_h = __builtin_amdgcn_mfma_f32_16x16x32_bf16(ah, whfrag[c], acc_h, 0,0,0);
    }
    #pragma unroll
    for(int r=0;r<4;r++) gates_lds[n][kgrp*4+r] = acc_e[r] + acc_h[r];
    __syncthreads();
    if(act){
      float iv = gates_lds[ej][erow];
      float fv = gates_lds[19+ej][erow];
      float gv = gates_lds[38+ej][erow];
      float ov = gates_lds[57+ej][erow];
      c_reg = sigf(fv)*c_reg + sigf(iv)*tanhfast(gv);
      float hv = sigf(ov)*tanhfast(c_reg);
      hx[(size_t)((t+1)&1)*16*KP + erow*KP + edim] = f2bf(hv);
      if(d==0){
        float wv = wprox[eb*T_ + t];
        hpad[hpf + (size_t)t*608] = f2bf(wv*hv);
      } else if(t < elen){
        int pos = elen-1-t;
        float wv = wprox[eb*T_ + pos];
        hpad[((size_t)eb*528 + 8 + pos)*608 + 300 + edim] = f2bf(wv*hv);
      }
    }
    __threadfence();   // release side: drain h stores device-wide before signaling
    __syncthreads();
    if(tid==0)
      __hip_atomic_fetch_add(flag, 1u, __ATOMIC_RELEASE, __HIP_MEMORY_SCOPE_AGENT);
  }
}

// ---------------- conv1d(k=3,pad=1) + bias + relu + max over t ----------------
__global__ __launch_bounds__(256) void k_conv(const unsigned short* __restrict__ hpad,
        const unsigned short* __restrict__ cwp, const float* __restrict__ cb,
        float* __restrict__ z){
  int blk = blockIdx.x;
  int b = blk/80; int rem = blk - b*80; int tt = rem/10; int ot = rem - tt*10;
  int tid=threadIdx.x, lane=tid&63, wid=tid>>6; int wt=wid>>1, wo=wid&1;
  int kgrp = lane>>4;
  __shared__ __align__(16) unsigned short h_s[66*32];
  __shared__ __align__(16) unsigned short Bs[3*64*32];
  f32x4 zero4 = {0.f,0.f,0.f,0.f};
  f32x4 acc[2][2];
  acc[0][0]=zero4; acc[0][1]=zero4; acc[1][0]=zero4; acc[1][1]=zero4;
  int t0 = tt*64, o0 = ot*64;
  const unsigned short* hrow = hpad + ((size_t)b*528 + 7 + t0)*608;
  for(int ic=0; ic<19; ic++){
    int i0 = ic*32;
    for(int id=tid; id<264; id+=256){
      int row=id>>2, seg=id&3;
      *(int4*)&h_s[id*8] = *(const int4*)&hrow[(size_t)row*608 + i0 + seg*8];
    }
    #pragma unroll
    for(int rr=0;rr<3;rr++){
      int id = wid*192 + rr*64 + lane;
      int kap = id>>8; int rrem = id&255; int orow=rrem>>2, seg=rrem&3;
      gload_lds16(cwp + ((size_t)kap*640 + o0 + orow)*608 + i0 + seg*8, (void*)&Bs[id*8]);
    }
    __syncthreads();
    #pragma unroll
    for(int kap=0;kap<3;kap++){
      s16x8 av[2], bv[2];
      #pragma unroll
      for(int mf=0;mf<2;mf++)
        av[mf] = *(const s16x8*)&h_s[(wt*32+mf*16+(lane&15)+kap)*32 + kgrp*8];
      #pragma unroll
      for(int nf=0;nf<2;nf++)
        bv[nf] = *(const s16x8*)&Bs[(kap*64 + wo*32+nf*16+(lane&15))*32 + kgrp*8];
      #pragma unroll
      for(int mf=0;mf<2;mf++)
        #pragma unroll
        for(int nf=0;nf<2;nf++)
          acc[mf][nf] = __builtin_amdgcn_mfma_f32_16x16x32_bf16(av[mf], bv[nf], acc[mf][nf], 0,0,0);
    }
    __syncthreads();
  }
  #pragma unroll
  for(int nf=0;nf<2;nf++){
    int o = o0 + wo*32 + nf*16 + (lane&15);
    float cbv = (o<600)? cb[o] : 0.f;
    float m = 0.f;
    #pragma unroll
    for(int mf=0;mf<2;mf++)
      #pragma unroll
      for(int r=0;r<4;r++){
        float v = acc[mf][nf][r] + cbv;
        v = v>0.f? v : 0.f;
        m = fmaxf(m, v);
      }
    m = fmaxf(m, __shfl_xor(m, 16));
    m = fmaxf(m, __shfl_xor(m, 32));
    if(kgrp==0) atomicMax((int*)&z[b*640 + o], __float_as_int(m));  // all v>=0: int cmp == float cmp
  }
}

// ---------------- final FC ----------------
__global__ void k_fc(const float* __restrict__ z, const float* __restrict__ fcw,
                     const float* __restrict__ fcb, float* __restrict__ out){
  int b = blockIdx.x; int lane = threadIdx.x;
  float a0=0.f,a1=0.f,a2=0.f;
  for(int o=lane;o<600;o+=64){
    float zv = z[b*640+o];
    a0 += zv*fcw[o]; a1 += zv*fcw[600+o]; a2 += zv*fcw[1200+o];
  }
  #pragma unroll
  for(int off=32;off>0;off>>=1){ a0+=__shfl_down(a0,off); a1+=__shfl_down(a1,off); a2+=__shfl_down(a2,off); }
  if(lane==0){ out[b*3+0]=a0+fcb[0]; out[b*3+1]=a1+fcb[1]; out[b*3+2]=a2+fcb[2]; }
}

extern "C" void kernel_launch(void* const* d_in, const int* in_sizes, int n_in,
                              void* d_out, int out_size, void* d_ws, size_t ws_size,
                              hipStream_t stream){
  const int*   text      = (const int*)d_in[0];
  const int*   aspect    = (const int*)d_in[1];
  const int*   left      = (const int*)d_in[2];
  const float* embedding = (const float*)d_in[3];
  const float* w_ih_f    = (const float*)d_in[4];
  const float* w_hh_f    = (const float*)d_in[5];
  const float* b_f       = (const float*)d_in[6];
  const float* w_ih_b    = (const float*)d_in[7];
  const float* w_hh_b    = (const float*)d_in[8];
  const float* b_b       = (const float*)d_in[9];
  const float* conv_w    = (const float*)d_in[10];
  const float* conv_b    = (const float*)d_in[11];
  const float* fc_w      = (const float*)d_in[12];
  const float* fc_b      = (const float*)d_in[13];
  float* out = (float*)d_out;
  char* ws = (char*)d_ws;
  size_t off = 0;
  auto alloc = [&](size_t bytes)->void*{ void* p = ws + off; off += (bytes + 255) & ~(size_t)255; return p; };
  unsigned short* embp  = (unsigned short*)alloc(2ull*M_*KP*2);      // 83.9 MB
  unsigned short* cwp   = (unsigned short*)alloc(3ull*640*608*2);    // 2.3 MB
  unsigned short* hpad  = (unsigned short*)alloc(128ull*528*608*2);  // 82.2 MB
  float*          wprox = (float*)alloc(128ull*512*4);               // 0.26 MB
  int*            lens  = (int*)alloc(384*4);
  unsigned short* hexch = (unsigned short*)alloc(16ull*2*16*KP*2);   // 0.66 MB
  unsigned int*   flags = (unsigned int*)alloc(64*4);
  float*          z     = (float*)alloc(128ull*640*4);               // 0.33 MB
  (void)in_sizes; (void)n_in; (void)out_size; (void)ws_size;
  // total ~170 MB of d_ws

  hipMemsetAsync(hpad,  0, 128ull*528*608*2, stream);
  hipMemsetAsync(hexch, 0, 16ull*2*16*KP*2,  stream);
  hipMemsetAsync(flags, 0, 64*4,             stream);
  hipMemsetAsync(z,     0, 128ull*640*4,     stream);

  k_len_prox<<<128, 64, 0, stream>>>(text, aspect, left, lens, wprox);
  k_emb<<<65536, 64, 0, stream>>>(text, embedding, lens, embp);
  k_cw<<<1920, 64, 0, stream>>>(conv_w, cwp);

  {
    const unsigned short* a0 = embp;
    const float* a1 = w_ih_f; const float* a2 = w_hh_f; const float* a3 = b_f;
    const float* a4 = w_ih_b; const float* a5 = w_hh_b; const float* a6 = b_b;
    const int* a7 = lens; const float* a8 = wprox;
    unsigned short* a9 = hexch; unsigned int* a10 = flags; unsigned short* a11 = hpad;
    void* ka[12] = {&a0,&a1,&a2,&a3,&a4,&a5,&a6,&a7,&a8,&a9,&a10,&a11};
    hipLaunchCooperativeKernel((void*)k_lstm, dim3(256), dim3(320), ka, 0, stream);
  }

  k_conv<<<10240, 256, 0, stream>>>(hpad, cwp, conv_b, z);
  k_fc<<<128, 64, 0, stream>>>(z, fc_w, fc_b, out);
}

// Round 3
// 19767.744 us; speedup vs baseline: 1.4051x; 1.4051x over previous
//
#include <hip/hip_runtime.h>
#include <stdint.h>
#include <stddef.h>

#define B_ 128
#define T_ 512
#define E_ 300
#define H_ 300
#define NG 1200   // 4H
#define KP 320    // padded K (300 -> 320)
#define M_ 65536  // B_*T_

typedef float f32x4 __attribute__((ext_vector_type(4)));
typedef short s16x8 __attribute__((ext_vector_type(8)));

static __device__ __forceinline__ unsigned short f2bf(float f){
  union { float f; unsigned u; } x; x.f = f;
  unsigned r = x.u + 0x7fffu + ((x.u >> 16) & 1u);  // RNE
  return (unsigned short)(r >> 16);
}
static __device__ __forceinline__ void gload_lds16(const void* g, void* l){
  __builtin_amdgcn_global_load_lds((const __attribute__((address_space(1))) unsigned int*)g,
                                   (__attribute__((address_space(3))) unsigned int*)l, 16, 0, 0);
}
static __device__ __forceinline__ float sigf(float x){ return 1.f/(1.f + __expf(-x)); }
static __device__ __forceinline__ float tanhfast(float x){ return 2.f/(1.f + __expf(-2.f*x)) - 1.f; }

// ---------------- lengths + proximity weights ----------------
__global__ void k_len_prox(const int* __restrict__ text, const int* __restrict__ aspect,
                           const int* __restrict__ left, int* __restrict__ lens,
                           float* __restrict__ wprox){
  int b = blockIdx.x; int lane = threadIdx.x;
  int c1=0,c2=0,c3=0;
  for(int t=lane;t<T_;t+=64){
    c1 += (text[b*T_+t]!=0); c2 += (aspect[b*T_+t]!=0); c3 += (left[b*T_+t]!=0);
  }
  #pragma unroll
  for(int o=32;o>0;o>>=1){ c1+=__shfl_down(c1,o); c2+=__shfl_down(c2,o); c3+=__shfl_down(c3,o); }
  __shared__ int sl[3];
  if(lane==0){ sl[0]=c1; sl[1]=c2; sl[2]=c3; lens[b]=c1; lens[128+b]=c2; lens[256+b]=c3; }
  __syncthreads();
  float tl=(float)sl[0]; float a0=(float)sl[2]; float a1=a0+(float)sl[1]-1.f; float ctx=tl-(float)sl[1];
  for(int t=lane;t<T_;t+=64){
    float j=(float)t, w;
    if(j<a0) w = 1.f-(a0-j)/ctx;
    else if(j<=a1) w = 0.f;
    else if(j<tl) w = 1.f-(j-a1)/ctx;
    else w = 0.f;
    wprox[b*T_+t]=w;
  }
}

// ---------------- embedding gather (fwd + length-reversed), bf16, K padded ----------------
__global__ void k_emb(const int* __restrict__ text, const float* __restrict__ emb,
                      const int* __restrict__ lens, unsigned short* __restrict__ embp){
  int m = blockIdx.x; int b = m>>9; int t = m&511; int lane=threadIdx.x;
  int idxf = text[m];
  int len = lens[b];
  int idxb = (t<len)? text[b*T_ + (len-1-t)] : -1;
  const float* rf = emb + (size_t)idxf*E_;
  const float* rb = emb + (size_t)(idxb<0?0:idxb)*E_;
  unsigned short* of = embp + (size_t)m*KP;
  unsigned short* ob = embp + ((size_t)M_ + m)*KP;
  for(int k=lane;k<KP;k+=64){
    of[k] = (k<E_)? f2bf(rf[k]) : (unsigned short)0;
    ob[k] = (k<E_ && idxb>=0)? f2bf(rb[k]) : (unsigned short)0;
  }
}

// ---------------- conv weight repack ----------------
__global__ void k_cw(const float* __restrict__ cw, unsigned short* __restrict__ out){
  int rid = blockIdx.x; int kap = rid/640; int o = rid-kap*640; int lane=threadIdx.x;
  unsigned short* dst = out + ((size_t)kap*640 + o)*608;
  for(int i=lane;i<608;i+=64)
    dst[i] = (o<600 && i<600)? f2bf(cw[((size_t)o*600+i)*3 + kap]) : (unsigned short)0;
}

// ---------------- weight pre-pack into MFMA A-frag layout ----------------
// qa: wpack[(d*16+w)*80 + g*20 + c][lane][8]  (row = g*300 + w*16 + (lane&15), k = (c%10)*32 + kgrp*8)
// stray: wstray[(d*16+w)*20 + c][lane][8]     (w<12: gate=w/3, dim=256+(w%3)*16+(lane&15); w>=12: zeros)
__global__ void k_prep(const float* __restrict__ wihf, const float* __restrict__ whhf,
                       const float* __restrict__ wihb, const float* __restrict__ whhb,
                       unsigned short* __restrict__ wpack, unsigned short* __restrict__ wstray){
  int bid = blockIdx.x; int lane = threadIdx.x;
  int kgrp = (lane>>4)&3; int r16 = lane&15;
  __align__(16) unsigned short v[8] = {0,0,0,0,0,0,0,0};
  if(bid < 2560){
    int d = bid/1280; int rem = bid - d*1280;
    int w = rem/80; rem -= w*80;
    int g = rem/20; int c = rem - g*20;
    const float* Wi = d? wihb : wihf;
    const float* Wh = d? whhb : whhf;
    int row = g*300 + w*16 + r16;   // always < 1200
    #pragma unroll
    for(int j=0;j<8;j++){
      int k = (c%10)*32 + kgrp*8 + j;
      float f = 0.f;
      if(k < 300) f = (c<10) ? Wi[(size_t)row*300 + k] : Wh[(size_t)row*300 + k];
      v[j] = f2bf(f);
    }
    unsigned short* dst = wpack + (((size_t)(d*16+w)*80 + g*20 + c)*64 + lane)*8;
    *(int4*)dst = *(int4*)v;
  } else {
    int b2 = bid - 2560;
    int d = b2/320; int rem = b2 - d*320;
    int w = rem/20; int c = rem - w*20;
    if(w < 12){
      const float* Wi = d? wihb : wihf;
      const float* Wh = d? whhb : whhf;
      int gate = w/3; int dim = 256 + (w - gate*3)*16 + r16;
      if(dim < 300){
        int row = gate*300 + dim;
        #pragma unroll
        for(int j=0;j<8;j++){
          int k = (c%10)*32 + kgrp*8 + j;
          float f = 0.f;
          if(k < 300) f = (c<10) ? Wi[(size_t)row*300 + k] : Wh[(size_t)row*300 + k];
          v[j] = f2bf(f);
        }
      }
    }
    unsigned short* dst = wstray + (((size_t)(d*16+w)*20 + c)*64 + lane)*8;
    *(int4*)dst = *(int4*)v;
  }
}

// ---------------- bidirectional LSTM: 16 independent WGs, all dims per WG ----------------
// grid 16 = d(2) x batch-group g(8); 1024 threads = 16 waves.
// Wave w: quad qa = dims w*16..w*16+15, all 4 gates, weights in 320 VGPRs (A-operand frags).
// Stray dims 256..299: 12 M-blocks, wave w<12 streams weights from L2, epilogue via gates2 LDS.
// h exchanged via double-buffered LDS; 2 barriers/step; NO cross-WG communication.
__global__ __launch_bounds__(1024, 4) void k_lstm2(
    const unsigned short* __restrict__ embp,
    const unsigned short* __restrict__ wpack,
    const unsigned short* __restrict__ wstray,
    const float* __restrict__ bf, const float* __restrict__ bb,
    const int* __restrict__ lens, const float* __restrict__ wprox,
    unsigned short* __restrict__ hpad){
  int bid = blockIdx.x;
  int d = bid >> 3, g = bid & 7;
  int tid = threadIdx.x;
  int w = tid >> 6, lane = tid & 63;
  int kgrp = (lane>>4)&3, bcol = lane&15;

  __shared__ __align__(16) unsigned short e_lds[2][16][328];
  __shared__ __align__(16) unsigned short h_lds[2][16][328];
  __shared__ float gates2[4][16][48];

  // zero h_lds (both buffers; cols>=300 stay zero forever -> no NaN*0 into MFMA)
  {
    unsigned int* hz = (unsigned int*)&h_lds[0][0][0];
    for(int i=tid; i<5248; i+=1024) hz[i] = 0u;
  }

  // qa weight frags -> registers (pre-packed layout, contiguous dwordx4 loads)
  const unsigned short* wq = wpack + ((size_t)(d*16+w)*80)*64*8 + (size_t)lane*8;
  s16x8 qa[4][20];
  #pragma unroll
  for(int fgc=0; fgc<80; fgc++)
    ((s16x8*)qa)[fgc] = *(const s16x8*)(wq + (size_t)fgc*64*8);

  const unsigned short* wsb = wstray + ((size_t)(d*16+w)*20)*64*8 + (size_t)lane*8;
  const float* bias = d? bb : bf;
  float bias_r[4][4];
  #pragma unroll
  for(int g_=0; g_<4; g_++)
    #pragma unroll
    for(int r=0;r<4;r++)
      bias_r[g_][r] = bias[g_*300 + w*16 + kgrp*4 + r];

  int b_glob = g*16 + bcol;
  int elenA = lens[b_glob];
  float c_r[4] = {0.f,0.f,0.f,0.f};

  // epilogue-B mapping (dims 256..299)
  int dlB = tid>>4, bB = tid&15;
  bool actB = (tid < 704);            // dlB < 44
  int bB_glob = g*16 + bB;
  int elenB = actB ? lens[bB_glob] : 1;
  float biasB[4] = {0.f,0.f,0.f,0.f};
  float c2 = 0.f;
  if(actB){
    #pragma unroll
    for(int g_=0; g_<4; g_++) biasB[g_] = bias[g_*300 + 256 + dlB];
  }

  // e staging map: 640 16B segments = 16 rows x 40
  int srow = tid/40, scol = tid - srow*40;
  const unsigned short* ebase = embp + ((size_t)d*M_ + (size_t)(g*16)*T_)*KP;
  size_t esrc = (size_t)srow*T_*KP + (size_t)scol*8;
  if(tid < 640){
    int4 ev = *(const int4*)&ebase[esrc];
    *(int4*)&e_lds[0][srow][scol*8] = ev;
  }
  __syncthreads();

  for(int t=0; t<T_; t++){
    int cur = t&1, nxt = cur^1;
    // prefetch next e tile into regs (hide HBM/L2 latency under MFMA phase)
    int4 evn;
    int tn = (t+1 < T_) ? t+1 : t;
    if(tid < 640) evn = *(const int4*)&ebase[esrc + (size_t)tn*KP];

    f32x4 acc0 = {bias_r[0][0],bias_r[0][1],bias_r[0][2],bias_r[0][3]};
    f32x4 acc1 = {bias_r[1][0],bias_r[1][1],bias_r[1][2],bias_r[1][3]};
    f32x4 acc2 = {bias_r[2][0],bias_r[2][1],bias_r[2][2],bias_r[2][3]};
    f32x4 acc3 = {bias_r[3][0],bias_r[3][1],bias_r[3][2],bias_r[3][3]};
    f32x4 accs = {0.f,0.f,0.f,0.f};

    if(w < 12){
      #pragma unroll
      for(int c=0;c<20;c++){
        s16x8 bv = (c<10)
          ? *(const s16x8*)&e_lds[cur][bcol][c*32 + kgrp*8]
          : *(const s16x8*)&h_lds[cur][bcol][(c-10)*32 + kgrp*8];
        s16x8 sw = *(const s16x8*)(wsb + (size_t)c*64*8);
        acc0 = __builtin_amdgcn_mfma_f32_16x16x32_bf16(qa[0][c], bv, acc0, 0,0,0);
        acc1 = __builtin_amdgcn_mfma_f32_16x16x32_bf16(qa[1][c], bv, acc1, 0,0,0);
        acc2 = __builtin_amdgcn_mfma_f32_16x16x32_bf16(qa[2][c], bv, acc2, 0,0,0);
        acc3 = __builtin_amdgcn_mfma_f32_16x16x32_bf16(qa[3][c], bv, acc3, 0,0,0);
        accs = __builtin_amdgcn_mfma_f32_16x16x32_bf16(sw,      bv, accs, 0,0,0);
      }
      int gate = w/3; int dl0 = (w - gate*3)*16 + kgrp*4;
      *(f32x4*)&gates2[gate][bcol][dl0] = accs;
    } else {
      #pragma unroll
      for(int c=0;c<20;c++){
        s16x8 bv = (c<10)
          ? *(const s16x8*)&e_lds[cur][bcol][c*32 + kgrp*8]
          : *(const s16x8*)&h_lds[cur][bcol][(c-10)*32 + kgrp*8];
        acc0 = __builtin_amdgcn_mfma_f32_16x16x32_bf16(qa[0][c], bv, acc0, 0,0,0);
        acc1 = __builtin_amdgcn_mfma_f32_16x16x32_bf16(qa[1][c], bv, acc1, 0,0,0);
        acc2 = __builtin_amdgcn_mfma_f32_16x16x32_bf16(qa[2][c], bv, acc2, 0,0,0);
        acc3 = __builtin_amdgcn_mfma_f32_16x16x32_bf16(qa[3][c], bv, acc3, 0,0,0);
      }
    }
    __syncthreads();   // gates2 visible to ep-B; all reads of [cur] buffers done

    // ---- epilogue A: dims w*16 + kgrp*4 + r (all < 256), in-register gates ----
    {
      float hv4[4];
      #pragma unroll
      for(int r=0;r<4;r++){
        float iv = acc0[r], fv = acc1[r], gv = acc2[r], ov = acc3[r];
        c_r[r] = sigf(fv)*c_r[r] + sigf(iv)*tanhfast(gv);
        hv4[r] = sigf(ov)*tanhfast(c_r[r]);
      }
      int dim0 = w*16 + kgrp*4;
      __align__(8) unsigned short hb[4];
      #pragma unroll
      for(int r=0;r<4;r++) hb[r] = f2bf(hv4[r]);
      *(int2*)&h_lds[nxt][bcol][dim0] = *(int2*)hb;
      if(d==0){
        float wv = wprox[b_glob*T_ + t];
        __align__(8) unsigned short ob[4];
        #pragma unroll
        for(int r=0;r<4;r++) ob[r] = f2bf(wv*hv4[r]);
        *(int2*)&hpad[((size_t)b_glob*528 + 8 + t)*608 + dim0] = *(int2*)ob;
      } else if(t < elenA){
        int pos = elenA-1-t;
        float wv = wprox[b_glob*T_ + pos];
        __align__(8) unsigned short ob[4];
        #pragma unroll
        for(int r=0;r<4;r++) ob[r] = f2bf(wv*hv4[r]);
        *(int2*)&hpad[((size_t)b_glob*528 + 8 + pos)*608 + 300 + dim0] = *(int2*)ob;
      }
    }
    // ---- epilogue B: dims 256+dlB (dlB<44) via gates2 ----
    if(actB){
      float iv = gates2[0][bB][dlB] + biasB[0];
      float fv = gates2[1][bB][dlB] + biasB[1];
      float gv = gates2[2][bB][dlB] + biasB[2];
      float ov = gates2[3][bB][dlB] + biasB[3];
      c2 = sigf(fv)*c2 + sigf(iv)*tanhfast(gv);
      float hv = sigf(ov)*tanhfast(c2);
      h_lds[nxt][bB][256+dlB] = f2bf(hv);
      if(d==0){
        float wv = wprox[bB_glob*T_ + t];
        hpad[((size_t)bB_glob*528 + 8 + t)*608 + 256 + dlB] = f2bf(wv*hv);
      } else if(t < elenB){
        int pos = elenB-1-t;
        float wv = wprox[bB_glob*T_ + pos];
        hpad[((size_t)bB_glob*528 + 8 + pos)*608 + 300 + 256 + dlB] = f2bf(wv*hv);
      }
    }
    // write prefetched e tile
    if(tid < 640) *(int4*)&e_lds[nxt][srow][scol*8] = evn;
    __syncthreads();   // h_lds[nxt], e_lds[nxt] complete
  }
}

// ---------------- conv1d(k=3,pad=1) + bias + relu + max over t ----------------
__global__ __launch_bounds__(256) void k_conv(const unsigned short* __restrict__ hpad,
        const unsigned short* __restrict__ cwp, const float* __restrict__ cb,
        float* __restrict__ z){
  int blk = blockIdx.x;
  int b = blk/80; int rem = blk - b*80; int tt = rem/10; int ot = rem - tt*10;
  int tid=threadIdx.x, lane=tid&63, wid=tid>>6; int wt=wid>>1, wo=wid&1;
  int kgrp = lane>>4;
  __shared__ __align__(16) unsigned short h_s[66*32];
  __shared__ __align__(16) unsigned short Bs[3*64*32];
  f32x4 zero4 = {0.f,0.f,0.f,0.f};
  f32x4 acc[2][2];
  acc[0][0]=zero4; acc[0][1]=zero4; acc[1][0]=zero4; acc[1][1]=zero4;
  int t0 = tt*64, o0 = ot*64;
  const unsigned short* hrow = hpad + ((size_t)b*528 + 7 + t0)*608;
  for(int ic=0; ic<19; ic++){
    int i0 = ic*32;
    for(int id=tid; id<264; id+=256){
      int row=id>>2, seg=id&3;
      *(int4*)&h_s[id*8] = *(const int4*)&hrow[(size_t)row*608 + i0 + seg*8];
    }
    #pragma unroll
    for(int rr=0;rr<3;rr++){
      int id = wid*192 + rr*64 + lane;
      int kap = id>>8; int rrem = id&255; int orow=rrem>>2, seg=rrem&3;
      gload_lds16(cwp + ((size_t)kap*640 + o0 + orow)*608 + i0 + seg*8, (void*)&Bs[id*8]);
    }
    __syncthreads();
    #pragma unroll
    for(int kap=0;kap<3;kap++){
      s16x8 av[2], bv[2];
      #pragma unroll
      for(int mf=0;mf<2;mf++)
        av[mf] = *(const s16x8*)&h_s[(wt*32+mf*16+(lane&15)+kap)*32 + kgrp*8];
      #pragma unroll
      for(int nf=0;nf<2;nf++)
        bv[nf] = *(const s16x8*)&Bs[(kap*64 + wo*32+nf*16+(lane&15))*32 + kgrp*8];
      #pragma unroll
      for(int mf=0;mf<2;mf++)
        #pragma unroll
        for(int nf=0;nf<2;nf++)
          acc[mf][nf] = __builtin_amdgcn_mfma_f32_16x16x32_bf16(av[mf], bv[nf], acc[mf][nf], 0,0,0);
    }
    __syncthreads();
  }
  #pragma unroll
  for(int nf=0;nf<2;nf++){
    int o = o0 + wo*32 + nf*16 + (lane&15);
    float cbv = (o<600)? cb[o] : 0.f;
    float m = 0.f;
    #pragma unroll
    for(int mf=0;mf<2;mf++)
      #pragma unroll
      for(int r=0;r<4;r++){
        float v = acc[mf][nf][r] + cbv;
        v = v>0.f? v : 0.f;
        m = fmaxf(m, v);
      }
    m = fmaxf(m, __shfl_xor(m, 16));
    m = fmaxf(m, __shfl_xor(m, 32));
    if(kgrp==0) atomicMax((int*)&z[b*640 + o], __float_as_int(m));
  }
}

// ---------------- final FC ----------------
__global__ void k_fc(const float* __restrict__ z, const float* __restrict__ fcw,
                     const float* __restrict__ fcb, float* __restrict__ out){
  int b = blockIdx.x; int lane = threadIdx.x;
  float a0=0.f,a1=0.f,a2=0.f;
  for(int o=lane;o<600;o+=64){
    float zv = z[b*640+o];
    a0 += zv*fcw[o]; a1 += zv*fcw[600+o]; a2 += zv*fcw[1200+o];
  }
  #pragma unroll
  for(int off=32;off>0;off>>=1){ a0+=__shfl_down(a0,off); a1+=__shfl_down(a1,off); a2+=__shfl_down(a2,off); }
  if(lane==0){ out[b*3+0]=a0+fcb[0]; out[b*3+1]=a1+fcb[1]; out[b*3+2]=a2+fcb[2]; }
}

extern "C" void kernel_launch(void* const* d_in, const int* in_sizes, int n_in,
                              void* d_out, int out_size, void* d_ws, size_t ws_size,
                              hipStream_t stream){
  const int*   text      = (const int*)d_in[0];
  const int*   aspect    = (const int*)d_in[1];
  const int*   left      = (const int*)d_in[2];
  const float* embedding = (const float*)d_in[3];
  const float* w_ih_f    = (const float*)d_in[4];
  const float* w_hh_f    = (const float*)d_in[5];
  const float* b_f       = (const float*)d_in[6];
  const float* w_ih_b    = (const float*)d_in[7];
  const float* w_hh_b    = (const float*)d_in[8];
  const float* b_b       = (const float*)d_in[9];
  const float* conv_w    = (const float*)d_in[10];
  const float* conv_b    = (const float*)d_in[11];
  const float* fc_w      = (const float*)d_in[12];
  const float* fc_b      = (const float*)d_in[13];
  float* out = (float*)d_out;
  char* ws = (char*)d_ws;
  size_t off = 0;
  auto alloc = [&](size_t bytes)->void*{ void* p = ws + off; off += (bytes + 255) & ~(size_t)255; return p; };
  unsigned short* embp  = (unsigned short*)alloc(2ull*M_*KP*2);      // 83.9 MB
  unsigned short* cwp   = (unsigned short*)alloc(3ull*640*608*2);    // 2.3 MB
  unsigned short* hpad  = (unsigned short*)alloc(128ull*528*608*2);  // 82.2 MB
  float*          wprox = (float*)alloc(128ull*512*4);
  int*            lens  = (int*)alloc(384*4);
  unsigned short* wpack = (unsigned short*)alloc(2ull*16*80*64*8*2); // 2.6 MB
  unsigned short* wstray= (unsigned short*)alloc(2ull*16*20*64*8*2); // 0.66 MB
  float*          z     = (float*)alloc(128ull*640*4);
  (void)in_sizes; (void)n_in; (void)out_size; (void)ws_size;
  // total ~172 MB of d_ws

  hipMemsetAsync(hpad, 0, 128ull*528*608*2, stream);
  hipMemsetAsync(z,    0, 128ull*640*4,     stream);

  k_len_prox<<<128, 64, 0, stream>>>(text, aspect, left, lens, wprox);
  k_emb<<<65536, 64, 0, stream>>>(text, embedding, lens, embp);
  k_cw<<<1920, 64, 0, stream>>>(conv_w, cwp);
  k_prep<<<3200, 64, 0, stream>>>(w_ih_f, w_hh_f, w_ih_b, w_hh_b, wpack, wstray);

  k_lstm2<<<16, 1024, 0, stream>>>(embp, wpack, wstray, b_f, b_b, lens, wprox, hpad);

  k_conv<<<10240, 256, 0, stream>>>(hpad, cwp, conv_b, z);
  k_fc<<<128, 64, 0, stream>>>(z, fc_w, fc_b, out);
}